// Round 17
// baseline (24.300 us; speedup 1.0000x reference)
//
#include <hip/hip_runtime.h>
#include <cstdint>

#define T_STEPS 16
#define V_VECS  1024
#define D_DIM   128
#define B_BATCH 2048
#define BCAP    2048          // per-t list capacity (bulletproof: n <= B)

typedef float f32x2 __attribute__((ext_vector_type(2)));

// ---------------------------------------------------------------------------
// k_score: grid (16 vtiles, 16 t, 2 z), block 256 = 16(tv) x 16(tb).
// r16 skeleton (24.2us) + packed-FMA k-loop: acc as float2 pairs so the
// compiler emits v_pk_fma_f32 (2 FMAs/instr, gfx90a+) -> 8 pk_fma per k
// instead of 16 v_fmac (halves k-loop VALU time). pk_fma is fused like the
// contracted scalar path => bit-identical scores.
// All other structure identical to r16: int4 idx loads; barrier-light
// bucketing; A-prefetch above phase 0; T14 issue-early X loads (main +
// half chunk); invn reduce overlapped with Xs writes; r13 balance scheme
// (64-b chunk + 32-b half chunk, overflow inline-staged). Cross-block
// visibility via the KERNEL BOUNDARY only (rounds 4-6 lesson).
// ---------------------------------------------------------------------------
__global__ __launch_bounds__(256) void k_score(const float* __restrict__ X,
                                               const float* __restrict__ L,
                                               const int* __restrict__ idx,
                                               unsigned long long* __restrict__ partial,
                                               int* __restrict__ counts) {
    __shared__ __align__(16) float As[D_DIM][64];   // 32 KB
    __shared__ __align__(16) float Xs[D_DIM][64];   // 32 KB
    __shared__ float npart[4][64];                  // 1 KB
    __shared__ float invn_s[64];
    __shared__ unsigned short blist[BCAP];          // 4 KB
    __shared__ int wcnt[8][4];

    const int t    = blockIdx.y;
    const int vt   = blockIdx.x;
    const int v0   = vt * 64;
    const int z    = blockIdx.z;
    const int tid  = threadIdx.x;
    const int lane = tid & 63;
    const int w    = tid >> 6;

    // ---- A-tile prefetch (independent of phase 0 -> issue first) ----
    const float4* LA = (const float4*)(L + (size_t)(t * V_VECS + v0) * D_DIM);
    float4 areg[8];
    #pragma unroll
    for (int p = 0; p < 8; ++p) areg[p] = LA[lane * 32 + (w + 4 * p)];

    // ---- phase 0: barrier-light bucketing (idx via int4; b = tid*8 + r) ----
    const int4* idx4 = (const int4*)idx;
    const int4 ia = idx4[tid * 2];
    const int4 ib = idx4[tid * 2 + 1];
    const int iv8[8] = {ia.x, ia.y, ia.z, ia.w, ib.x, ib.y, ib.z, ib.w};
    bool mm[8]; int wpre[8];
    #pragma unroll
    for (int r = 0; r < 8; ++r) {
        const bool m = (iv8[r] == t);
        const unsigned long long bal = __ballot(m);
        mm[r]   = m;
        wpre[r] = __popcll(bal & ((1ull << lane) - 1ull));
        if (lane == 0) wcnt[r][w] = __popcll(bal);
    }
    __syncthreads();
    int run = 0;
    #pragma unroll
    for (int r = 0; r < 8; ++r) {
        int base = run;
        #pragma unroll
        for (int w2 = 0; w2 < 4; ++w2) {
            const int c = wcnt[r][w2];      // LDS broadcast (uniform)
            if (w2 < w) base += c;
            run += c;
        }
        if (mm[r]) blist[base + wpre[r]] = (unsigned short)(tid * 8 + r);
    }
    const int n = run;
    if (vt == 0 && z == 0 && tid == 0) counts[t] = n;   // before early return
    if (z * 64 >= n) return;             // uniform across blocks of t

    __syncthreads();                     // blist visible to all threads

    const float4* XA = (const float4*)X;

    // ---- T14 issue-early: main-chunk AND half-chunk X loads ----
    const int cs0 = z * 64;
    const int bg0 = (cs0 + lane < n) ? (int)blist[cs0 + lane] : -1;
    const float4* xr0 = XA + (size_t)(bg0 < 0 ? 0 : bg0) * 32;
    float4 xreg[8];
    #pragma unroll
    for (int p = 0; p < 8; ++p) {
        const int k4 = w + 4 * p;
        xreg[p] = (bg0 >= 0) ? xr0[k4] : make_float4(0.f, 0.f, 0.f, 0.f);
    }
    const int hs   = 128 + z * 32;
    const int hrow = tid >> 3;           // 0..31
    const int hk8  = tid & 7;            // 0..7
    const int hbg  = (hs < n && hs + hrow < n) ? (int)blist[hs + hrow] : -1;
    const float4* hxr = XA + (size_t)(hbg < 0 ? 0 : hbg) * 32;
    float4 hxreg[4];
    #pragma unroll
    for (int p = 0; p < 4; ++p) {
        hxreg[p] = (hbg >= 0) ? hxr[hk8 + 8 * p] : make_float4(0.f, 0.f, 0.f, 0.f);
    }

    // ---- phase 1: write prefetched A^T (k-major) + norm partials ----
    float ss = 0.f;
    #pragma unroll
    for (int p = 0; p < 8; ++p) {
        const int k4 = w + 4 * p;              // 0..31
        const float4 g = areg[p];
        As[4 * k4 + 0][lane] = g.x;
        As[4 * k4 + 1][lane] = g.y;
        As[4 * k4 + 2][lane] = g.z;
        As[4 * k4 + 3][lane] = g.w;
        ss += g.x * g.x + g.y * g.y + g.z * g.z + g.w * g.w;
    }
    npart[w][lane] = ss;
    __syncthreads();

    // ---- invn reduce (tid<64) OVERLAPPED with Xs writes (disjoint LDS) ----
    if (tid < 64) {
        const float s = npart[0][tid] + npart[1][tid] + npart[2][tid] + npart[3][tid];
        invn_s[tid] = rsqrtf(fmaxf(s, 1e-12f));
    }
    #pragma unroll
    for (int p = 0; p < 8; ++p) {
        const int k4 = w + 4 * p;
        const float4 g = xreg[p];
        Xs[4 * k4 + 0][lane] = g.x;
        Xs[4 * k4 + 1][lane] = g.y;
        Xs[4 * k4 + 2][lane] = g.z;
        Xs[4 * k4 + 3][lane] = g.w;
    }
    __syncthreads();                     // Xs + invn_s ready

    const int tv = tid & 15;     // v-group: v = v0 + tv*4 + i
    const int tb = tid >> 4;     // b-group

    const float4 inv4 = *(const float4*)&invn_s[tv * 4];
    const float invp[4] = {inv4.x, inv4.y, inv4.z, inv4.w};

    // ---- phase 2a: main 64-b chunk (packed-FMA k-loop) ----
    {
        f32x2 acc2[4][2] = {};
        #pragma unroll 16
        for (int k = 0; k < D_DIM; ++k) {
            const float4 av = *(const float4*)&As[k][tv * 4];
            const float4 xb = *(const float4*)&Xs[k][tb * 4];
            const float a[4] = {av.x, av.y, av.z, av.w};
            const f32x2 x01 = {xb.x, xb.y};
            const f32x2 x23 = {xb.z, xb.w};
            #pragma unroll
            for (int i = 0; i < 4; ++i) {
                const f32x2 ai = {a[i], a[i]};
                acc2[i][0] += ai * x01;      // v_pk_fma_f32
                acc2[i][1] += ai * x23;
            }
        }

        #pragma unroll
        for (int j = 0; j < 4; ++j) {
            float s = ((j < 2) ? acc2[0][0][j & 1] : acc2[0][1][j & 1]) * invp[0];
            int   c = v0 + tv * 4;
            #pragma unroll
            for (int i = 1; i < 4; ++i) {
                const float aij = (j < 2) ? acc2[i][0][j & 1] : acc2[i][1][j & 1];
                const float si = aij * invp[i];
                const int   ci = v0 + tv * 4 + i;
                if (si > s) { s = si; c = ci; }      // strict: lowest v wins tie
            }
            #pragma unroll
            for (int m = 8; m >= 1; m >>= 1) {       // reduce across tv lanes
                const float u  = __shfl_xor(s, m);
                const int   cu = __shfl_xor(c, m);
                if (u > s || (u == s && cu < c)) { s = u; c = cu; }
            }
            if (tv == 0) {
                const int bi = cs0 + tb * 4 + j;
                if (bi < n) {
                    unsigned int ub = __float_as_uint(s);
                    ub = (ub & 0x80000000u) ? ~ub : (ub | 0x80000000u);
                    const unsigned long long key =
                        ((unsigned long long)ub << 32) |
                        ((unsigned long long)(unsigned)(1023 - c) << 16) |
                        (unsigned long long)blist[bi];
                    partial[((size_t)vt * T_STEPS + t) * BCAP + bi] = key;
                }
            }
        }
    }

    // ---- phase 2a': overflow chunks (n > 192; ~6 sigma rare), inline-staged ----
    for (int cs = 192 + z * 64; cs < n; cs += 128) {
        __syncthreads();         // prior Xs reads settled

        const int brow = cs + lane;
        const int bg = (brow < n) ? (int)blist[brow] : -1;
        const float4* xr = XA + (size_t)(bg < 0 ? 0 : bg) * 32;
        #pragma unroll
        for (int p = 0; p < 8; ++p) {
            const int k4 = w + 4 * p;
            float4 g = make_float4(0.f, 0.f, 0.f, 0.f);
            if (bg >= 0) g = xr[k4];
            Xs[4 * k4 + 0][lane] = g.x;
            Xs[4 * k4 + 1][lane] = g.y;
            Xs[4 * k4 + 2][lane] = g.z;
            Xs[4 * k4 + 3][lane] = g.w;
        }
        __syncthreads();

        f32x2 acc2[4][2] = {};
        #pragma unroll 16
        for (int k = 0; k < D_DIM; ++k) {
            const float4 av = *(const float4*)&As[k][tv * 4];
            const float4 xb = *(const float4*)&Xs[k][tb * 4];
            const float a[4] = {av.x, av.y, av.z, av.w};
            const f32x2 x01 = {xb.x, xb.y};
            const f32x2 x23 = {xb.z, xb.w};
            #pragma unroll
            for (int i = 0; i < 4; ++i) {
                const f32x2 ai = {a[i], a[i]};
                acc2[i][0] += ai * x01;
                acc2[i][1] += ai * x23;
            }
        }

        #pragma unroll
        for (int j = 0; j < 4; ++j) {
            float s = ((j < 2) ? acc2[0][0][j & 1] : acc2[0][1][j & 1]) * invp[0];
            int   c = v0 + tv * 4;
            #pragma unroll
            for (int i = 1; i < 4; ++i) {
                const float aij = (j < 2) ? acc2[i][0][j & 1] : acc2[i][1][j & 1];
                const float si = aij * invp[i];
                const int   ci = v0 + tv * 4 + i;
                if (si > s) { s = si; c = ci; }
            }
            #pragma unroll
            for (int m = 8; m >= 1; m >>= 1) {
                const float u  = __shfl_xor(s, m);
                const int   cu = __shfl_xor(c, m);
                if (u > s || (u == s && cu < c)) { s = u; c = cu; }
            }
            if (tv == 0) {
                const int bi = cs + tb * 4 + j;
                if (bi < n) {
                    unsigned int ub = __float_as_uint(s);
                    ub = (ub & 0x80000000u) ? ~ub : (ub | 0x80000000u);
                    const unsigned long long key =
                        ((unsigned long long)ub << 32) |
                        ((unsigned long long)(unsigned)(1023 - c) << 16) |
                        (unsigned long long)blist[bi];
                    partial[((size_t)vt * T_STEPS + t) * BCAP + bi] = key;
                }
            }
        }
    }

    // ---- phase 2b: 32-b half chunk [128+z*32, 160+z*32), prefetched ----
    if (hs < n) {
        __syncthreads();         // prior Xs reads settled

        #pragma unroll
        for (int p = 0; p < 4; ++p) {
            const int k4 = hk8 + 8 * p;      // 0..31
            const float4 g = hxreg[p];
            Xs[4 * k4 + 0][hrow] = g.x;
            Xs[4 * k4 + 1][hrow] = g.y;
            Xs[4 * k4 + 2][hrow] = g.z;
            Xs[4 * k4 + 3][hrow] = g.w;
        }
        __syncthreads();

        const int tb2 = tid >> 4;            // 0..15, 2 cols each
        f32x2 hacc2[4] = {};
        #pragma unroll 16
        for (int k = 0; k < D_DIM; ++k) {
            const float4 av = *(const float4*)&As[k][tv * 4];
            const float2 xb = *(const float2*)&Xs[k][tb2 * 2];
            const float a[4] = {av.x, av.y, av.z, av.w};
            const f32x2 x01 = {xb.x, xb.y};
            #pragma unroll
            for (int i = 0; i < 4; ++i) {
                const f32x2 ai = {a[i], a[i]};
                hacc2[i] += ai * x01;        // v_pk_fma_f32
            }
        }

        #pragma unroll
        for (int j = 0; j < 2; ++j) {
            float s = hacc2[0][j] * invp[0];
            int   c = v0 + tv * 4;
            #pragma unroll
            for (int i = 1; i < 4; ++i) {
                const float si = hacc2[i][j] * invp[i];
                const int   ci = v0 + tv * 4 + i;
                if (si > s) { s = si; c = ci; }      // strict: lowest v wins tie
            }
            #pragma unroll
            for (int m = 8; m >= 1; m >>= 1) {       // reduce across tv lanes
                const float u  = __shfl_xor(s, m);
                const int   cu = __shfl_xor(c, m);
                if (u > s || (u == s && cu < c)) { s = u; c = cu; }
            }
            if (tv == 0) {
                const int bi = hs + tb2 * 2 + j;
                if (bi < n) {
                    unsigned int ub = __float_as_uint(s);
                    ub = (ub & 0x80000000u) ? ~ub : (ub | 0x80000000u);
                    const unsigned long long key =
                        ((unsigned long long)ub << 32) |
                        ((unsigned long long)(unsigned)(1023 - c) << 16) |
                        (unsigned long long)blist[bi];
                    partial[((size_t)vt * T_STEPS + t) * BCAP + bi] = key;
                }
            }
        }
    }
}

// ---------------------------------------------------------------------------
// k_gather: grid (3 bi-chunks, 16 t) + safety loop (stride 192). Reads
// counts/partial across the kernel boundary. Per valid bi: max-reduce the 16
// vt-keys (ties -> lower v, matches jnp.argmax), decode (b, v), copy the raw
// winning vector (bit-exact).
// ---------------------------------------------------------------------------
__global__ __launch_bounds__(256) void k_gather(const float* __restrict__ L,
                                                const int* __restrict__ counts,
                                                const unsigned long long* __restrict__ partial,
                                                float* __restrict__ out) {
    __shared__ int vArr[64];
    __shared__ int bArr[64];

    const int t   = blockIdx.y;
    const int n   = counts[t];
    const int tid = threadIdx.x;
    const int l32 = tid & 31;

    for (int cs = blockIdx.x * 64; cs < n; cs += 192) {
        const int nb = min(64, n - cs);
        if (tid < nb) {
            const int bi = cs + tid;
            unsigned long long best = partial[(size_t)t * BCAP + bi];   // vt=0
            #pragma unroll
            for (int q = 1; q < 16; ++q) {
                const unsigned long long k2 =
                    partial[((size_t)q * T_STEPS + t) * BCAP + bi];
                if (k2 > best) best = k2;
            }
            vArr[tid] = 1023 - (int)((best >> 16) & 0xffffull);
            bArr[tid] = (int)(best & 0xffffull);
        }
        __syncthreads();
        for (int q = tid >> 5; q < nb; q += 8) {
            const int b = bArr[q], v = vArr[q];
            ((float4*)out)[b * 32 + l32] =
                ((const float4*)L)[(size_t)(t * V_VECS + v) * 32 + l32];
        }
        __syncthreads();
    }
}

extern "C" void kernel_launch(void* const* d_in, const int* in_sizes, int n_in,
                              void* d_out, int out_size, void* d_ws, size_t ws_size,
                              hipStream_t stream) {
    const float* X  = (const float*)d_in[0];   // (B, D, 1) f32
    const float* L  = (const float*)d_in[1];   // (T, V, D) f32
    const int* idx  = (const int*)d_in[2];     // (B,) int
    float* out      = (float*)d_out;           // (B, D) f32

    char* ws = (char*)d_ws;
    int* counts               = (int*)ws;                              // 64 B
    unsigned long long* part  = (unsigned long long*)(ws + 4096);      // 4 MiB

    hipLaunchKernelGGL(k_score,  dim3(16, 16, 2), dim3(256), 0, stream,
                       X, L, idx, part, counts);
    hipLaunchKernelGGL(k_gather, dim3(3, 16),     dim3(256), 0, stream,
                       L, counts, part, out);
}

// Round 18
// 24.225 us; speedup vs baseline: 1.0031x; 1.0031x over previous
//
#include <hip/hip_runtime.h>
#include <cstdint>

#define T_STEPS 16
#define V_VECS  1024
#define D_DIM   128
#define B_BATCH 2048
#define BCAP    2048          // per-t list capacity (bulletproof: n <= B)

// ---------------------------------------------------------------------------
// k_score: grid (16 vtiles, 16 t, 2 z), block 256 = 16(tv) x 16(tb).
// Final keeper (r16 structure, best measured 24.2us):
//   - int4 idx loads, barrier-light ballot bucketing (one barrier, uniform
//     prefix from wcnt) -> deterministic identical blist in every block of t;
//   - A-tile prefetch issued above phase 0 (latency hidden under ballots);
//   - T14 issue-early X loads (main 64-b chunk + 32-b half chunk) right
//     after the blist barrier; write-late into LDS;
//   - invn reduce overlapped with Xs register->LDS writes (disjoint LDS);
//   - r13 balance: z-block runs main chunk [z*64,..) + half chunk
//     [128+z*32,..); overflow (n>192, ~6 sigma) inline-staged loop;
//   - epilogue: invnorm scale, per-thread argmax over 4 v, shfl_xor butterfly
//     across tv lanes (strict >, ties -> lowest v, matches jnp.argmax),
//     plain store of packed (ordered_score:32 | (1023-v):16 | b:16) key.
// Cross-block visibility via the KERNEL BOUNDARY only (intra-kernel
// protocols failed rounds 4-6). Output is a bit-exact copy of the winning
// raw vector -> absmax 0.
// Measured verdicts that define this design: 8 waves/CU optimal (r7-r9 vs
// r10/r11/r14); X belongs in LDS (r10); split-K regresses (r14); packed FMA
// neutral (r17) -> kernel is latency-bound, not pipe-bound.
// ---------------------------------------------------------------------------
__global__ __launch_bounds__(256) void k_score(const float* __restrict__ X,
                                               const float* __restrict__ L,
                                               const int* __restrict__ idx,
                                               unsigned long long* __restrict__ partial,
                                               int* __restrict__ counts) {
    __shared__ __align__(16) float As[D_DIM][64];   // 32 KB
    __shared__ __align__(16) float Xs[D_DIM][64];   // 32 KB
    __shared__ float npart[4][64];                  // 1 KB
    __shared__ float invn_s[64];
    __shared__ unsigned short blist[BCAP];          // 4 KB
    __shared__ int wcnt[8][4];

    const int t    = blockIdx.y;
    const int vt   = blockIdx.x;
    const int v0   = vt * 64;
    const int z    = blockIdx.z;
    const int tid  = threadIdx.x;
    const int lane = tid & 63;
    const int w    = tid >> 6;

    // ---- A-tile prefetch (independent of phase 0 -> issue first) ----
    const float4* LA = (const float4*)(L + (size_t)(t * V_VECS + v0) * D_DIM);
    float4 areg[8];
    #pragma unroll
    for (int p = 0; p < 8; ++p) areg[p] = LA[lane * 32 + (w + 4 * p)];

    // ---- phase 0: barrier-light bucketing (idx via int4; b = tid*8 + r) ----
    const int4* idx4 = (const int4*)idx;
    const int4 ia = idx4[tid * 2];
    const int4 ib = idx4[tid * 2 + 1];
    const int iv8[8] = {ia.x, ia.y, ia.z, ia.w, ib.x, ib.y, ib.z, ib.w};
    bool mm[8]; int wpre[8];
    #pragma unroll
    for (int r = 0; r < 8; ++r) {
        const bool m = (iv8[r] == t);
        const unsigned long long bal = __ballot(m);
        mm[r]   = m;
        wpre[r] = __popcll(bal & ((1ull << lane) - 1ull));
        if (lane == 0) wcnt[r][w] = __popcll(bal);
    }
    __syncthreads();
    int run = 0;
    #pragma unroll
    for (int r = 0; r < 8; ++r) {
        int base = run;
        #pragma unroll
        for (int w2 = 0; w2 < 4; ++w2) {
            const int c = wcnt[r][w2];      // LDS broadcast (uniform)
            if (w2 < w) base += c;
            run += c;
        }
        if (mm[r]) blist[base + wpre[r]] = (unsigned short)(tid * 8 + r);
    }
    const int n = run;
    if (vt == 0 && z == 0 && tid == 0) counts[t] = n;   // before early return
    if (z * 64 >= n) return;             // uniform across blocks of t

    __syncthreads();                     // blist visible to all threads

    const float4* XA = (const float4*)X;

    // ---- T14 issue-early: main-chunk AND half-chunk X loads ----
    const int cs0 = z * 64;
    const int bg0 = (cs0 + lane < n) ? (int)blist[cs0 + lane] : -1;
    const float4* xr0 = XA + (size_t)(bg0 < 0 ? 0 : bg0) * 32;
    float4 xreg[8];
    #pragma unroll
    for (int p = 0; p < 8; ++p) {
        const int k4 = w + 4 * p;
        xreg[p] = (bg0 >= 0) ? xr0[k4] : make_float4(0.f, 0.f, 0.f, 0.f);
    }
    const int hs   = 128 + z * 32;
    const int hrow = tid >> 3;           // 0..31
    const int hk8  = tid & 7;            // 0..7
    const int hbg  = (hs < n && hs + hrow < n) ? (int)blist[hs + hrow] : -1;
    const float4* hxr = XA + (size_t)(hbg < 0 ? 0 : hbg) * 32;
    float4 hxreg[4];
    #pragma unroll
    for (int p = 0; p < 4; ++p) {
        hxreg[p] = (hbg >= 0) ? hxr[hk8 + 8 * p] : make_float4(0.f, 0.f, 0.f, 0.f);
    }

    // ---- phase 1: write prefetched A^T (k-major) + norm partials ----
    float ss = 0.f;
    #pragma unroll
    for (int p = 0; p < 8; ++p) {
        const int k4 = w + 4 * p;              // 0..31
        const float4 g = areg[p];
        As[4 * k4 + 0][lane] = g.x;
        As[4 * k4 + 1][lane] = g.y;
        As[4 * k4 + 2][lane] = g.z;
        As[4 * k4 + 3][lane] = g.w;
        ss += g.x * g.x + g.y * g.y + g.z * g.z + g.w * g.w;
    }
    npart[w][lane] = ss;
    __syncthreads();

    // ---- invn reduce (tid<64) OVERLAPPED with Xs writes (disjoint LDS) ----
    if (tid < 64) {
        const float s = npart[0][tid] + npart[1][tid] + npart[2][tid] + npart[3][tid];
        invn_s[tid] = rsqrtf(fmaxf(s, 1e-12f));
    }
    #pragma unroll
    for (int p = 0; p < 8; ++p) {
        const int k4 = w + 4 * p;
        const float4 g = xreg[p];
        Xs[4 * k4 + 0][lane] = g.x;
        Xs[4 * k4 + 1][lane] = g.y;
        Xs[4 * k4 + 2][lane] = g.z;
        Xs[4 * k4 + 3][lane] = g.w;
    }
    __syncthreads();                     // Xs + invn_s ready

    const int tv = tid & 15;     // v-group: v = v0 + tv*4 + i
    const int tb = tid >> 4;     // b-group

    const float4 inv4 = *(const float4*)&invn_s[tv * 4];
    const float invp[4] = {inv4.x, inv4.y, inv4.z, inv4.w};

    // ---- phase 2a: main 64-b chunk (k-loop identical to r7..r16) ----
    {
        float acc[4][4] = {};
        #pragma unroll 16
        for (int k = 0; k < D_DIM; ++k) {
            const float4 av = *(const float4*)&As[k][tv * 4];
            const float4 xb = *(const float4*)&Xs[k][tb * 4];
            const float a[4] = {av.x, av.y, av.z, av.w};
            const float x[4] = {xb.x, xb.y, xb.z, xb.w};
            #pragma unroll
            for (int i = 0; i < 4; ++i)
                #pragma unroll
                for (int j = 0; j < 4; ++j)
                    acc[i][j] += a[i] * x[j];
        }

        #pragma unroll
        for (int j = 0; j < 4; ++j) {
            float s = acc[0][j] * invp[0];
            int   c = v0 + tv * 4;
            #pragma unroll
            for (int i = 1; i < 4; ++i) {
                const float si = acc[i][j] * invp[i];
                const int   ci = v0 + tv * 4 + i;
                if (si > s) { s = si; c = ci; }      // strict: lowest v wins tie
            }
            #pragma unroll
            for (int m = 8; m >= 1; m >>= 1) {       // reduce across tv lanes
                const float u  = __shfl_xor(s, m);
                const int   cu = __shfl_xor(c, m);
                if (u > s || (u == s && cu < c)) { s = u; c = cu; }
            }
            if (tv == 0) {
                const int bi = cs0 + tb * 4 + j;
                if (bi < n) {
                    unsigned int ub = __float_as_uint(s);
                    ub = (ub & 0x80000000u) ? ~ub : (ub | 0x80000000u);
                    const unsigned long long key =
                        ((unsigned long long)ub << 32) |
                        ((unsigned long long)(unsigned)(1023 - c) << 16) |
                        (unsigned long long)blist[bi];
                    partial[((size_t)vt * T_STEPS + t) * BCAP + bi] = key;
                }
            }
        }
    }

    // ---- phase 2a': overflow chunks (n > 192; ~6 sigma rare), inline-staged ----
    for (int cs = 192 + z * 64; cs < n; cs += 128) {
        __syncthreads();         // prior Xs reads settled

        const int brow = cs + lane;
        const int bg = (brow < n) ? (int)blist[brow] : -1;
        const float4* xr = XA + (size_t)(bg < 0 ? 0 : bg) * 32;
        #pragma unroll
        for (int p = 0; p < 8; ++p) {
            const int k4 = w + 4 * p;
            float4 g = make_float4(0.f, 0.f, 0.f, 0.f);
            if (bg >= 0) g = xr[k4];
            Xs[4 * k4 + 0][lane] = g.x;
            Xs[4 * k4 + 1][lane] = g.y;
            Xs[4 * k4 + 2][lane] = g.z;
            Xs[4 * k4 + 3][lane] = g.w;
        }
        __syncthreads();

        float acc[4][4] = {};
        #pragma unroll 16
        for (int k = 0; k < D_DIM; ++k) {
            const float4 av = *(const float4*)&As[k][tv * 4];
            const float4 xb = *(const float4*)&Xs[k][tb * 4];
            const float a[4] = {av.x, av.y, av.z, av.w};
            const float x[4] = {xb.x, xb.y, xb.z, xb.w};
            #pragma unroll
            for (int i = 0; i < 4; ++i)
                #pragma unroll
                for (int j = 0; j < 4; ++j)
                    acc[i][j] += a[i] * x[j];
        }

        #pragma unroll
        for (int j = 0; j < 4; ++j) {
            float s = acc[0][j] * invp[0];
            int   c = v0 + tv * 4;
            #pragma unroll
            for (int i = 1; i < 4; ++i) {
                const float si = acc[i][j] * invp[i];
                const int   ci = v0 + tv * 4 + i;
                if (si > s) { s = si; c = ci; }
            }
            #pragma unroll
            for (int m = 8; m >= 1; m >>= 1) {
                const float u  = __shfl_xor(s, m);
                const int   cu = __shfl_xor(c, m);
                if (u > s || (u == s && cu < c)) { s = u; c = cu; }
            }
            if (tv == 0) {
                const int bi = cs + tb * 4 + j;
                if (bi < n) {
                    unsigned int ub = __float_as_uint(s);
                    ub = (ub & 0x80000000u) ? ~ub : (ub | 0x80000000u);
                    const unsigned long long key =
                        ((unsigned long long)ub << 32) |
                        ((unsigned long long)(unsigned)(1023 - c) << 16) |
                        (unsigned long long)blist[bi];
                    partial[((size_t)vt * T_STEPS + t) * BCAP + bi] = key;
                }
            }
        }
    }

    // ---- phase 2b: 32-b half chunk [128+z*32, 160+z*32), prefetched ----
    if (hs < n) {
        __syncthreads();         // prior Xs reads settled

        #pragma unroll
        for (int p = 0; p < 4; ++p) {
            const int k4 = hk8 + 8 * p;      // 0..31
            const float4 g = hxreg[p];
            Xs[4 * k4 + 0][hrow] = g.x;
            Xs[4 * k4 + 1][hrow] = g.y;
            Xs[4 * k4 + 2][hrow] = g.z;
            Xs[4 * k4 + 3][hrow] = g.w;
        }
        __syncthreads();

        const int tb2 = tid >> 4;            // 0..15, 2 cols each
        float hacc[4][2] = {};
        #pragma unroll 16
        for (int k = 0; k < D_DIM; ++k) {
            const float4 av = *(const float4*)&As[k][tv * 4];
            const float2 xb = *(const float2*)&Xs[k][tb2 * 2];
            const float a[4] = {av.x, av.y, av.z, av.w};
            const float x[2] = {xb.x, xb.y};
            #pragma unroll
            for (int i = 0; i < 4; ++i)
                #pragma unroll
                for (int j = 0; j < 2; ++j)
                    hacc[i][j] += a[i] * x[j];
        }

        #pragma unroll
        for (int j = 0; j < 2; ++j) {
            float s = hacc[0][j] * invp[0];
            int   c = v0 + tv * 4;
            #pragma unroll
            for (int i = 1; i < 4; ++i) {
                const float si = hacc[i][j] * invp[i];
                const int   ci = v0 + tv * 4 + i;
                if (si > s) { s = si; c = ci; }      // strict: lowest v wins tie
            }
            #pragma unroll
            for (int m = 8; m >= 1; m >>= 1) {       // reduce across tv lanes
                const float u  = __shfl_xor(s, m);
                const int   cu = __shfl_xor(c, m);
                if (u > s || (u == s && cu < c)) { s = u; c = cu; }
            }
            if (tv == 0) {
                const int bi = hs + tb2 * 2 + j;
                if (bi < n) {
                    unsigned int ub = __float_as_uint(s);
                    ub = (ub & 0x80000000u) ? ~ub : (ub | 0x80000000u);
                    const unsigned long long key =
                        ((unsigned long long)ub << 32) |
                        ((unsigned long long)(unsigned)(1023 - c) << 16) |
                        (unsigned long long)blist[bi];
                    partial[((size_t)vt * T_STEPS + t) * BCAP + bi] = key;
                }
            }
        }
    }
}

// ---------------------------------------------------------------------------
// k_gather: grid (3 bi-chunks, 16 t) + safety loop (stride 192). Reads
// counts/partial across the kernel boundary. Per valid bi: max-reduce the 16
// vt-keys (ties -> lower v, matches jnp.argmax), decode (b, v), copy the raw
// winning vector (bit-exact).
// ---------------------------------------------------------------------------
__global__ __launch_bounds__(256) void k_gather(const float* __restrict__ L,
                                                const int* __restrict__ counts,
                                                const unsigned long long* __restrict__ partial,
                                                float* __restrict__ out) {
    __shared__ int vArr[64];
    __shared__ int bArr[64];

    const int t   = blockIdx.y;
    const int n   = counts[t];
    const int tid = threadIdx.x;
    const int l32 = tid & 31;

    for (int cs = blockIdx.x * 64; cs < n; cs += 192) {
        const int nb = min(64, n - cs);
        if (tid < nb) {
            const int bi = cs + tid;
            unsigned long long best = partial[(size_t)t * BCAP + bi];   // vt=0
            #pragma unroll
            for (int q = 1; q < 16; ++q) {
                const unsigned long long k2 =
                    partial[((size_t)q * T_STEPS + t) * BCAP + bi];
                if (k2 > best) best = k2;
            }
            vArr[tid] = 1023 - (int)((best >> 16) & 0xffffull);
            bArr[tid] = (int)(best & 0xffffull);
        }
        __syncthreads();
        for (int q = tid >> 5; q < nb; q += 8) {
            const int b = bArr[q], v = vArr[q];
            ((float4*)out)[b * 32 + l32] =
                ((const float4*)L)[(size_t)(t * V_VECS + v) * 32 + l32];
        }
        __syncthreads();
    }
}

extern "C" void kernel_launch(void* const* d_in, const int* in_sizes, int n_in,
                              void* d_out, int out_size, void* d_ws, size_t ws_size,
                              hipStream_t stream) {
    const float* X  = (const float*)d_in[0];   // (B, D, 1) f32
    const float* L  = (const float*)d_in[1];   // (T, V, D) f32
    const int* idx  = (const int*)d_in[2];     // (B,) int
    float* out      = (float*)d_out;           // (B, D) f32

    char* ws = (char*)d_ws;
    int* counts               = (int*)ws;                              // 64 B
    unsigned long long* part  = (unsigned long long*)(ws + 4096);      // 4 MiB

    hipLaunchKernelGGL(k_score,  dim3(16, 16, 2), dim3(256), 0, stream,
                       X, L, idx, part, counts);
    hipLaunchKernelGGL(k_gather, dim3(3, 16),     dim3(256), 0, stream,
                       L, counts, part, out);
}